// Round 1
// baseline (657.943 us; speedup 1.0000x reference)
//
#include <hip/hip_runtime.h>
#include <hip/hip_bf16.h>
#include <cstdint>

#define NV 64000      // B*N nodes
#define DD 64         // hidden dim
#define FF 3          // input features
#define NE 1000000    // edges
#define BB 32         // batch (graphs)
#define SS 50         // timesteps
#define NN 2000       // nodes per graph

// ---------------------------------------------------------------------------
// Detect whether edge_index arrived as int64 (odd int32 words all zero) or
// int32. Branch is wave-uniform in all consumers.
// ---------------------------------------------------------------------------
__global__ void detect_i64_kernel(const int* __restrict__ ei, int* __restrict__ flag) {
    __shared__ int nz;
    int t = threadIdx.x;
    if (t == 0) nz = 0;
    __syncthreads();
    int local = 0;
    for (int i = t; i < 4096; i += blockDim.x)
        local |= (ei[2 * i + 1] != 0);
    if (local) atomicOr(&nz, 1);
    __syncthreads();
    if (t == 0) *flag = (nz == 0) ? 1 : 0;
}

// degi[i] = 1 (self loop)
__global__ void init_deg_kernel(int* __restrict__ degi) {
    int i = blockIdx.x * blockDim.x + threadIdx.x;
    if (i < NV) degi[i] = 1;
}

// degi[dst] += 1 over all edges
__global__ void deg_kernel(const int* __restrict__ ei32, const int* __restrict__ flag,
                           int* __restrict__ degi) {
    const long long* ei64 = (const long long*)ei32;
    const int is64 = *flag;
    int stride = gridDim.x * blockDim.x;
    for (int e = blockIdx.x * blockDim.x + threadIdx.x; e < NE; e += stride) {
        int d = is64 ? (int)ei64[NE + e] : ei32[NE + e];
        if ((unsigned)d < NV) atomicAdd(&degi[d], 1);
    }
}

__global__ void dinv_kernel(const int* __restrict__ degi, float* __restrict__ dinv) {
    int i = blockIdx.x * blockDim.x + threadIdx.x;
    if (i < NV) dinv[i] = rsqrtf((float)degi[i]);
}

// h0[node*3+f] = mean over S of x[b][s][n][f]
__global__ void tmean_kernel(const float* __restrict__ x, float* __restrict__ h0) {
    int tid = blockIdx.x * blockDim.x + threadIdx.x;  // over NV*FF
    if (tid >= NV * FF) return;
    int nf = tid % (NN * FF);
    int b  = tid / (NN * FF);
    const float* xp = x + (size_t)b * SS * NN * FF + nf;
    float acc = 0.f;
    #pragma unroll
    for (int s = 0; s < SS; ++s) acc += xp[(size_t)s * NN * FF];
    h0[tid] = acc * (1.0f / SS);
}

// g = dinv[node] * (h0 @ W1); write g into bufA (gather source) and bufB
// (raw-sum accumulator, self-loop contribution pre-folded).
__global__ void transform1_kernel(const float* __restrict__ h0, const float* __restrict__ dinv,
                                  const float* __restrict__ W1,
                                  float* __restrict__ gA, float* __restrict__ rawB) {
    int tid = blockIdx.x * blockDim.x + threadIdx.x;  // NV*DD
    if (tid >= NV * DD) return;
    int node = tid >> 6, d = tid & 63;
    float di = dinv[node];
    float g = di * (h0[node * 3 + 0] * W1[d] +
                    h0[node * 3 + 1] * W1[64 + d] +
                    h0[node * 3 + 2] * W1[128 + d]);
    gA[tid] = g;
    rawB[tid] = g;
}

// One 64-lane wave per edge: coalesced 256B gather of g[src], coalesced
// 64x fp32 atomicAdd into raw[dst].
__global__ __launch_bounds__(256) void scatter_kernel(const int* __restrict__ ei32,
                                                      const int* __restrict__ flag,
                                                      const float* __restrict__ g,
                                                      float* __restrict__ raw) {
    const long long* ei64 = (const long long*)ei32;
    const int is64 = *flag;
    int lane = threadIdx.x & 63;
    int wave = (blockIdx.x * blockDim.x + threadIdx.x) >> 6;
    int nwaves = (gridDim.x * blockDim.x) >> 6;
    for (int e = wave; e < NE; e += nwaves) {
        int s, t;
        if (is64) { s = (int)ei64[e]; t = (int)ei64[NE + e]; }
        else      { s = ei32[e];      t = ei32[NE + e]; }
        if ((unsigned)s < NV && (unsigned)t < NV) {
            float v = g[((size_t)s << 6) + lane];
            atomicAdd(&raw[((size_t)t << 6) + lane], v);
        }
    }
}

// h1 = relu(dinv[node]*raw + b1[d]), in place
__global__ void finish1_kernel(float* __restrict__ rawB, const float* __restrict__ dinv,
                               const float* __restrict__ b1) {
    int tid = blockIdx.x * blockDim.x + threadIdx.x;
    if (tid >= NV * DD) return;
    int node = tid >> 6, d = tid & 63;
    float v = dinv[node] * rawB[tid] + b1[d];
    rawB[tid] = v > 0.f ? v : 0.f;
}

// g2 = dinv[node] * (h1 @ W2); W2 + 4 h1-rows staged in LDS.
// Writes bufA (gather source) and bufB (raw-sum accumulator w/ self loop).
// Each block reads exactly the 4 rows it overwrites -> no cross-block hazard.
__global__ __launch_bounds__(256) void transform2_kernel(const float* __restrict__ dinv,
                                                         const float* __restrict__ W2,
                                                         float* __restrict__ gA,
                                                         float* __restrict__ h1rawB) {
    __shared__ float W2s[64 * 64];
    __shared__ float rows[4 * 64];
    int t = threadIdx.x;
    for (int i = t; i < 64 * 64; i += 256) W2s[i] = W2[i];
    int base = blockIdx.x * 256;  // element base: 4 nodes * 64
    rows[t] = h1rawB[base + t];
    __syncthreads();
    int sub = t >> 6, d = t & 63;
    const float* r = &rows[sub * 64];
    float acc = 0.f;
    #pragma unroll 8
    for (int k = 0; k < 64; ++k) acc += r[k] * W2s[k * 64 + d];
    int node = (base >> 6) + sub;
    float g = dinv[node] * acc;
    gA[base + t] = g;
    h1rawB[base + t] = g;
}

// Fused: h2 = relu(dinv*raw2 + b2); per-graph mean over N; head @ Wh + bh.
__global__ __launch_bounds__(256) void pool_head_kernel(const float* __restrict__ rawB,
                                                        const float* __restrict__ dinv,
                                                        const float* __restrict__ b2,
                                                        const float* __restrict__ Wh,
                                                        const float* __restrict__ bh,
                                                        float* __restrict__ out) {
    __shared__ float part[4][64];
    __shared__ float pooled[64];
    int b = blockIdx.x;
    int t = threadIdx.x;
    int d = t & 63, p = t >> 6;
    float bias = b2[d];
    float acc = 0.f;
    for (int n = p; n < NN; n += 4) {
        int node = b * NN + n;
        float v = dinv[node] * rawB[((size_t)node << 6) + d] + bias;
        acc += v > 0.f ? v : 0.f;
    }
    part[p][d] = acc;
    __syncthreads();
    if (t < 64) {
        float s = part[0][t] + part[1][t] + part[2][t] + part[3][t];
        pooled[t] = s * (1.0f / NN);
    }
    __syncthreads();
    if (t < 2) {
        float o = bh[t];
        for (int k = 0; k < 64; ++k) o += pooled[k] * Wh[k * 2 + t];
        out[b * 2 + t] = o;
    }
}

extern "C" void kernel_launch(void* const* d_in, const int* in_sizes, int n_in,
                              void* d_out, int out_size, void* d_ws, size_t ws_size,
                              hipStream_t stream) {
    const float* x  = (const float*)d_in[0];
    const int*   ei = (const int*)d_in[1];
    const float* W1 = (const float*)d_in[2];
    const float* b1 = (const float*)d_in[3];
    const float* W2 = (const float*)d_in[4];
    const float* b2 = (const float*)d_in[5];
    const float* Wh = (const float*)d_in[6];
    const float* bh = (const float*)d_in[7];
    float* out = (float*)d_out;

    float* ws   = (float*)d_ws;
    float* bufA = ws;                       // NV*DD
    float* bufB = bufA + (size_t)NV * DD;   // NV*DD
    float* h0   = bufB + (size_t)NV * DD;   // NV*FF
    float* dinv = h0 + (size_t)NV * FF;     // NV
    int*   degi = (int*)(dinv + NV);        // NV
    int*   flag = degi + NV;                // 1

    detect_i64_kernel<<<1, 256, 0, stream>>>(ei, flag);
    init_deg_kernel<<<(NV + 255) / 256, 256, 0, stream>>>(degi);
    tmean_kernel<<<(NV * FF + 255) / 256, 256, 0, stream>>>(x, h0);
    deg_kernel<<<2048, 256, 0, stream>>>(ei, flag, degi);
    dinv_kernel<<<(NV + 255) / 256, 256, 0, stream>>>(degi, dinv);

    // Layer 1
    transform1_kernel<<<NV * DD / 256, 256, 0, stream>>>(h0, dinv, W1, bufA, bufB);
    scatter_kernel<<<2048, 256, 0, stream>>>(ei, flag, bufA, bufB);
    finish1_kernel<<<NV * DD / 256, 256, 0, stream>>>(bufB, dinv, b1);

    // Layer 2
    transform2_kernel<<<NV * DD / 256, 256, 0, stream>>>(dinv, W2, bufA, bufB);
    scatter_kernel<<<2048, 256, 0, stream>>>(ei, flag, bufA, bufB);

    // Pool + head
    pool_head_kernel<<<BB, 256, 0, stream>>>(bufB, dinv, b2, Wh, bh, out);
}

// Round 2
// 528.232 us; speedup vs baseline: 1.2456x; 1.2456x over previous
//
#include <hip/hip_runtime.h>
#include <hip/hip_bf16.h>
#include <cstdint>

#define NV 64000      // B*N nodes
#define DD 64         // hidden dim
#define FF 3          // input features
#define NE 1000000    // edges
#define BB 32         // batch (graphs)
#define SS 50         // timesteps
#define NN 2000       // nodes per graph
#define SCAN_T 1024

// ---------------------------------------------------------------------------
// Detect whether edge_index arrived as int64 (odd int32 words all zero) or
// int32. Branch is wave-uniform in all consumers.
// ---------------------------------------------------------------------------
__global__ void detect_i64_kernel(const int* __restrict__ ei, int* __restrict__ flag) {
    __shared__ int nz;
    int t = threadIdx.x;
    if (t == 0) nz = 0;
    __syncthreads();
    int local = 0;
    for (int i = t; i < 4096; i += blockDim.x)
        local |= (ei[2 * i + 1] != 0);
    if (local) atomicOr(&nz, 1);
    __syncthreads();
    if (t == 0) *flag = (nz == 0) ? 1 : 0;
}

__global__ void zero_deg_kernel(int* __restrict__ degi) {
    int i = blockIdx.x * blockDim.x + threadIdx.x;
    if (i < NV) degi[i] = 0;
}

// Edge-only dst degree (self loop added later in dinv).
__global__ void deg_kernel(const int* __restrict__ ei32, const int* __restrict__ flag,
                           int* __restrict__ degi) {
    const long long* ei64 = (const long long*)ei32;
    const int is64 = *flag;
    int stride = gridDim.x * blockDim.x;
    for (int e = blockIdx.x * blockDim.x + threadIdx.x; e < NE; e += stride) {
        int d = is64 ? (int)ei64[NE + e] : ei32[NE + e];
        if ((unsigned)d < NV) atomicAdd(&degi[d], 1);
    }
}

__global__ void dinv_kernel(const int* __restrict__ degi, float* __restrict__ dinv) {
    int i = blockIdx.x * blockDim.x + threadIdx.x;
    if (i < NV) dinv[i] = rsqrtf((float)(degi[i] + 1));  // +1 self loop
}

// Single-block exclusive scan of degi -> rowptr (NV+1) and cursor copy.
__global__ __launch_bounds__(SCAN_T) void scan_kernel(const int* __restrict__ deg,
                                                      int* __restrict__ rowptr,
                                                      int* __restrict__ cursor) {
    __shared__ int lsum[SCAN_T];
    int t = threadIdx.x;
    const int CH = (NV + SCAN_T - 1) / SCAN_T;
    int beg = t * CH, end = beg + CH < NV ? beg + CH : NV;
    int s = 0;
    for (int i = beg; i < end; ++i) s += deg[i];
    lsum[t] = s;
    __syncthreads();
    for (int off = 1; off < SCAN_T; off <<= 1) {
        int v = (t >= off) ? lsum[t - off] : 0;
        __syncthreads();
        lsum[t] += v;
        __syncthreads();
    }
    int run = (t == 0) ? 0 : lsum[t - 1];
    for (int i = beg; i < end; ++i) {
        rowptr[i] = run;
        cursor[i] = run;
        run += deg[i];
    }
    if (t == SCAN_T - 1) rowptr[NV] = run;
}

// Bin src ids by dst into sorted_src (CSR column array).
__global__ void bin_kernel(const int* __restrict__ ei32, const int* __restrict__ flag,
                           int* __restrict__ cursor, int* __restrict__ sorted_src) {
    const long long* ei64 = (const long long*)ei32;
    const int is64 = *flag;
    int stride = gridDim.x * blockDim.x;
    for (int e = blockIdx.x * blockDim.x + threadIdx.x; e < NE; e += stride) {
        int s, d;
        if (is64) { s = (int)ei64[e]; d = (int)ei64[NE + e]; }
        else      { s = ei32[e];      d = ei32[NE + e]; }
        if ((unsigned)s < NV && (unsigned)d < NV) {
            int pos = atomicAdd(&cursor[d], 1);
            sorted_src[pos] = s;
        }
    }
}

// h0[node*3+f] = mean over S of x[b][s][n][f]
__global__ void tmean_kernel(const float* __restrict__ x, float* __restrict__ h0) {
    int tid = blockIdx.x * blockDim.x + threadIdx.x;  // over NV*FF
    if (tid >= NV * FF) return;
    int nf = tid % (NN * FF);
    int b  = tid / (NN * FF);
    const float* xp = x + (size_t)b * SS * NN * FF + nf;
    float acc = 0.f;
    #pragma unroll
    for (int s = 0; s < SS; ++s) acc += xp[(size_t)s * NN * FF];
    h0[tid] = acc * (1.0f / SS);
}

// g = dinv[node] * (h0 @ W1)
__global__ void transform1_kernel(const float* __restrict__ h0, const float* __restrict__ dinv,
                                  const float* __restrict__ W1, float* __restrict__ gA) {
    int tid = blockIdx.x * blockDim.x + threadIdx.x;  // NV*DD
    if (tid >= NV * DD) return;
    int node = tid >> 6, d = tid & 63;
    float di = dinv[node];
    gA[tid] = di * (h0[node * 3 + 0] * W1[d] +
                    h0[node * 3 + 1] * W1[64 + d] +
                    h0[node * 3 + 2] * W1[128 + d]);
}

// One wave per dst node: register-accumulate gathered g rows, one 256B store.
// Self loop pre-folded (acc starts at g[node]); dinv[dst] applied downstream.
__global__ __launch_bounds__(256) void agg_kernel(const int* __restrict__ rowptr,
                                                  const int* __restrict__ srcs,
                                                  const float* __restrict__ g,
                                                  float* __restrict__ raw) {
    int lane = threadIdx.x & 63;
    int node = (blockIdx.x * blockDim.x + threadIdx.x) >> 6;
    if (node >= NV) return;
    int beg = rowptr[node], end = rowptr[node + 1];
    float acc = g[((size_t)node << 6) + lane];  // self loop
    int e = beg;
    for (; e + 4 <= end; e += 4) {
        int s0 = srcs[e], s1 = srcs[e + 1], s2 = srcs[e + 2], s3 = srcs[e + 3];
        float v0 = g[((size_t)s0 << 6) + lane];
        float v1 = g[((size_t)s1 << 6) + lane];
        float v2 = g[((size_t)s2 << 6) + lane];
        float v3 = g[((size_t)s3 << 6) + lane];
        acc += v0 + v1 + v2 + v3;
    }
    for (; e < end; ++e) acc += g[((size_t)srcs[e] << 6) + lane];
    raw[((size_t)node << 6) + lane] = acc;
}

// Fused: h1 = relu(dinv*raw1 + b1); g2 = dinv * (h1 @ W2). W2 + 4 rows in LDS.
__global__ __launch_bounds__(256) void transform2_kernel(const float* __restrict__ raw1,
                                                         const float* __restrict__ dinv,
                                                         const float* __restrict__ b1,
                                                         const float* __restrict__ W2,
                                                         float* __restrict__ gA) {
    __shared__ float W2s[64 * 64];
    __shared__ float rows[4 * 64];
    int t = threadIdx.x;
    for (int i = t; i < 64 * 64; i += 256) W2s[i] = W2[i];
    int base = blockIdx.x * 256;
    int node0 = base >> 6;
    {
        int node = node0 + (t >> 6), d = t & 63;
        float v = dinv[node] * raw1[base + t] + b1[d];
        rows[t] = v > 0.f ? v : 0.f;
    }
    __syncthreads();
    int sub = t >> 6, d = t & 63;
    const float* r = &rows[sub * 64];
    float acc = 0.f;
    #pragma unroll 8
    for (int k = 0; k < 64; ++k) acc += r[k] * W2s[k * 64 + d];
    gA[base + t] = dinv[node0 + sub] * acc;
}

// Fused: h2 = relu(dinv*raw2 + b2); per-graph mean over N; head @ Wh + bh.
__global__ __launch_bounds__(256) void pool_head_kernel(const float* __restrict__ rawB,
                                                        const float* __restrict__ dinv,
                                                        const float* __restrict__ b2,
                                                        const float* __restrict__ Wh,
                                                        const float* __restrict__ bh,
                                                        float* __restrict__ out) {
    __shared__ float part[4][64];
    __shared__ float pooled[64];
    int b = blockIdx.x;
    int t = threadIdx.x;
    int d = t & 63, p = t >> 6;
    float bias = b2[d];
    float acc = 0.f;
    for (int n = p; n < NN; n += 4) {
        int node = b * NN + n;
        float v = dinv[node] * rawB[((size_t)node << 6) + d] + bias;
        acc += v > 0.f ? v : 0.f;
    }
    part[p][d] = acc;
    __syncthreads();
    if (t < 64) {
        float s = part[0][t] + part[1][t] + part[2][t] + part[3][t];
        pooled[t] = s * (1.0f / NN);
    }
    __syncthreads();
    if (t < 2) {
        float o = bh[t];
        for (int k = 0; k < 64; ++k) o += pooled[k] * Wh[k * 2 + t];
        out[b * 2 + t] = o;
    }
}

extern "C" void kernel_launch(void* const* d_in, const int* in_sizes, int n_in,
                              void* d_out, int out_size, void* d_ws, size_t ws_size,
                              hipStream_t stream) {
    const float* x  = (const float*)d_in[0];
    const int*   ei = (const int*)d_in[1];
    const float* W1 = (const float*)d_in[2];
    const float* b1 = (const float*)d_in[3];
    const float* W2 = (const float*)d_in[4];
    const float* b2 = (const float*)d_in[5];
    const float* Wh = (const float*)d_in[6];
    const float* bh = (const float*)d_in[7];
    float* out = (float*)d_out;

    float* ws   = (float*)d_ws;
    float* bufA = ws;                          // NV*DD  (g / gather source)
    float* bufB = bufA + (size_t)NV * DD;      // NV*DD  (raw aggregate)
    float* h0   = bufB + (size_t)NV * DD;      // NV*FF
    float* dinv = h0 + (size_t)NV * FF;        // NV
    int*   degi = (int*)(dinv + NV);           // NV
    int*   rowptr = degi + NV;                 // NV+1
    int*   cursor = rowptr + NV + 1;           // NV
    int*   sorted_src = cursor + NV;           // NE
    int*   flag = sorted_src + NE;             // 1

    // --- CSR build ---
    detect_i64_kernel<<<1, 256, 0, stream>>>(ei, flag);
    zero_deg_kernel<<<(NV + 255) / 256, 256, 0, stream>>>(degi);
    tmean_kernel<<<(NV * FF + 255) / 256, 256, 0, stream>>>(x, h0);
    deg_kernel<<<2048, 256, 0, stream>>>(ei, flag, degi);
    dinv_kernel<<<(NV + 255) / 256, 256, 0, stream>>>(degi, dinv);
    scan_kernel<<<1, SCAN_T, 0, stream>>>(degi, rowptr, cursor);
    bin_kernel<<<2048, 256, 0, stream>>>(ei, flag, cursor, sorted_src);

    // --- Layer 1 ---
    transform1_kernel<<<NV * DD / 256, 256, 0, stream>>>(h0, dinv, W1, bufA);
    agg_kernel<<<NV * 64 / 256, 256, 0, stream>>>(rowptr, sorted_src, bufA, bufB);

    // --- Layer 2 (relu/bias of layer 1 fused into transform) ---
    transform2_kernel<<<NV * DD / 256, 256, 0, stream>>>(bufB, dinv, b1, W2, bufA);
    agg_kernel<<<NV * 64 / 256, 256, 0, stream>>>(rowptr, sorted_src, bufA, bufB);

    // --- Pool + head ---
    pool_head_kernel<<<BB, 256, 0, stream>>>(bufB, dinv, b2, Wh, bh, out);
}

// Round 3
// 394.744 us; speedup vs baseline: 1.6668x; 1.3382x over previous
//
#include <hip/hip_runtime.h>
#include <hip/hip_bf16.h>
#include <cstdint>

#define NV 64000      // B*N nodes
#define DD 64         // hidden dim
#define FF 3          // input features
#define NE 1000000    // edges
#define BB 32         // batch (graphs)
#define SS 50         // timesteps
#define NN 2000       // nodes per graph
#define NBLK 250      // scan blocks: 250 * 256 == NV

// ---------------------------------------------------------------------------
// Detect whether edge_index arrived as int64 (odd int32 words all zero) or
// int32. Branch is wave-uniform in all consumers.
// ---------------------------------------------------------------------------
__global__ void detect_i64_kernel(const int* __restrict__ ei, int* __restrict__ flag) {
    __shared__ int nz;
    int t = threadIdx.x;
    if (t == 0) nz = 0;
    __syncthreads();
    int local = 0;
    for (int i = t; i < 4096; i += blockDim.x)
        local |= (ei[2 * i + 1] != 0);
    if (local) atomicOr(&nz, 1);
    __syncthreads();
    if (t == 0) *flag = (nz == 0) ? 1 : 0;
}

__global__ void zero_deg_kernel(int* __restrict__ degi) {
    int i = blockIdx.x * blockDim.x + threadIdx.x;
    if (i < NV) degi[i] = 0;
}

// Edge-only dst degree (self loop added later in dinv).
__global__ void deg_kernel(const int* __restrict__ ei32, const int* __restrict__ flag,
                           int* __restrict__ degi) {
    const long long* ei64 = (const long long*)ei32;
    const int is64 = *flag;
    int stride = gridDim.x * blockDim.x;
    for (int e = blockIdx.x * blockDim.x + threadIdx.x; e < NE; e += stride) {
        int d = is64 ? (int)ei64[NE + e] : ei32[NE + e];
        if ((unsigned)d < NV) atomicAdd(&degi[d], 1);
    }
}

__global__ void dinv_kernel(const int* __restrict__ degi, float* __restrict__ dinv) {
    int i = blockIdx.x * blockDim.x + threadIdx.x;
    if (i < NV) dinv[i] = rsqrtf((float)(degi[i] + 1));  // +1 self loop
}

// --- 3-phase hierarchical exclusive scan over degi (64000 = 250 x 256) ---
// Phase 1: per-block exclusive scan -> rowptr (local), block sums -> bsums.
__global__ __launch_bounds__(256) void scan1_kernel(const int* __restrict__ deg,
                                                    int* __restrict__ rowptr,
                                                    int* __restrict__ bsums) {
    __shared__ int ls[256];
    int t = threadIdx.x;
    int idx = blockIdx.x * 256 + t;
    int v = deg[idx];
    ls[t] = v;
    __syncthreads();
    #pragma unroll
    for (int off = 1; off < 256; off <<= 1) {
        int u = (t >= off) ? ls[t - off] : 0;
        __syncthreads();
        ls[t] += u;
        __syncthreads();
    }
    rowptr[idx] = ls[t] - v;  // exclusive, block-local
    if (t == 255) bsums[blockIdx.x] = ls[255];
}

// Phase 2: single block scans the 250 block sums -> boffs; total -> rowptr[NV].
__global__ __launch_bounds__(256) void scan2_kernel(const int* __restrict__ bsums,
                                                    int* __restrict__ boffs,
                                                    int* __restrict__ rowptr) {
    __shared__ int ls[256];
    int t = threadIdx.x;
    int v = (t < NBLK) ? bsums[t] : 0;
    ls[t] = v;
    __syncthreads();
    #pragma unroll
    for (int off = 1; off < 256; off <<= 1) {
        int u = (t >= off) ? ls[t - off] : 0;
        __syncthreads();
        ls[t] += u;
        __syncthreads();
    }
    if (t < NBLK) boffs[t] = ls[t] - v;
    if (t == NBLK - 1) rowptr[NV] = ls[t];
}

// Phase 3: add block offsets; emit final rowptr + cursor copy.
__global__ __launch_bounds__(256) void scan3_kernel(int* __restrict__ rowptr,
                                                    const int* __restrict__ boffs,
                                                    int* __restrict__ cursor) {
    int idx = blockIdx.x * 256 + threadIdx.x;
    int v = rowptr[idx] + boffs[blockIdx.x];
    rowptr[idx] = v;
    cursor[idx] = v;
}

// Bin src ids by dst into sorted_src (CSR column array).
__global__ void bin_kernel(const int* __restrict__ ei32, const int* __restrict__ flag,
                           int* __restrict__ cursor, int* __restrict__ sorted_src) {
    const long long* ei64 = (const long long*)ei32;
    const int is64 = *flag;
    int stride = gridDim.x * blockDim.x;
    for (int e = blockIdx.x * blockDim.x + threadIdx.x; e < NE; e += stride) {
        int s, d;
        if (is64) { s = (int)ei64[e]; d = (int)ei64[NE + e]; }
        else      { s = ei32[e];      d = ei32[NE + e]; }
        if ((unsigned)s < NV && (unsigned)d < NV) {
            int pos = atomicAdd(&cursor[d], 1);
            sorted_src[pos] = s;
        }
    }
}

// h0[node*3+f] = mean over S of x[b][s][n][f]
__global__ void tmean_kernel(const float* __restrict__ x, float* __restrict__ h0) {
    int tid = blockIdx.x * blockDim.x + threadIdx.x;  // over NV*FF
    if (tid >= NV * FF) return;
    int nf = tid % (NN * FF);
    int b  = tid / (NN * FF);
    const float* xp = x + (size_t)b * SS * NN * FF + nf;
    float acc = 0.f;
    #pragma unroll
    for (int s = 0; s < SS; ++s) acc += xp[(size_t)s * NN * FF];
    h0[tid] = acc * (1.0f / SS);
}

// g = dinv[node] * (h0 @ W1)
__global__ void transform1_kernel(const float* __restrict__ h0, const float* __restrict__ dinv,
                                  const float* __restrict__ W1, float* __restrict__ gA) {
    int tid = blockIdx.x * blockDim.x + threadIdx.x;  // NV*DD
    if (tid >= NV * DD) return;
    int node = tid >> 6, d = tid & 63;
    float di = dinv[node];
    gA[tid] = di * (h0[node * 3 + 0] * W1[d] +
                    h0[node * 3 + 1] * W1[64 + d] +
                    h0[node * 3 + 2] * W1[128 + d]);
}

// One wave per dst node: register-accumulate gathered g rows, one 256B store.
// Self loop pre-folded (acc starts at g[node]); dinv[dst] applied downstream.
__global__ __launch_bounds__(256) void agg_kernel(const int* __restrict__ rowptr,
                                                  const int* __restrict__ srcs,
                                                  const float* __restrict__ g,
                                                  float* __restrict__ raw) {
    int lane = threadIdx.x & 63;
    int node = (blockIdx.x * blockDim.x + threadIdx.x) >> 6;
    if (node >= NV) return;
    int beg = rowptr[node], end = rowptr[node + 1];
    float acc = g[((size_t)node << 6) + lane];  // self loop
    int e = beg;
    for (; e + 4 <= end; e += 4) {
        int s0 = srcs[e], s1 = srcs[e + 1], s2 = srcs[e + 2], s3 = srcs[e + 3];
        float v0 = g[((size_t)s0 << 6) + lane];
        float v1 = g[((size_t)s1 << 6) + lane];
        float v2 = g[((size_t)s2 << 6) + lane];
        float v3 = g[((size_t)s3 << 6) + lane];
        acc += v0 + v1 + v2 + v3;
    }
    for (; e < end; ++e) acc += g[((size_t)srcs[e] << 6) + lane];
    raw[((size_t)node << 6) + lane] = acc;
}

// Fused: h1 = relu(dinv*raw1 + b1); g2 = dinv * (h1 @ W2). W2 + 4 rows in LDS.
__global__ __launch_bounds__(256) void transform2_kernel(const float* __restrict__ raw1,
                                                         const float* __restrict__ dinv,
                                                         const float* __restrict__ b1,
                                                         const float* __restrict__ W2,
                                                         float* __restrict__ gA) {
    __shared__ float W2s[64 * 64];
    __shared__ float rows[4 * 64];
    int t = threadIdx.x;
    for (int i = t; i < 64 * 64; i += 256) W2s[i] = W2[i];
    int base = blockIdx.x * 256;
    int node0 = base >> 6;
    {
        int node = node0 + (t >> 6), d = t & 63;
        float v = dinv[node] * raw1[base + t] + b1[d];
        rows[t] = v > 0.f ? v : 0.f;
    }
    __syncthreads();
    int sub = t >> 6, d = t & 63;
    const float* r = &rows[sub * 64];
    float acc = 0.f;
    #pragma unroll 8
    for (int k = 0; k < 64; ++k) acc += r[k] * W2s[k * 64 + d];
    gA[base + t] = dinv[node0 + sub] * acc;
}

// Fused: h2 = relu(dinv*raw2 + b2); per-graph mean over N; head @ Wh + bh.
__global__ __launch_bounds__(256) void pool_head_kernel(const float* __restrict__ rawB,
                                                        const float* __restrict__ dinv,
                                                        const float* __restrict__ b2,
                                                        const float* __restrict__ Wh,
                                                        const float* __restrict__ bh,
                                                        float* __restrict__ out) {
    __shared__ float part[4][64];
    __shared__ float pooled[64];
    int b = blockIdx.x;
    int t = threadIdx.x;
    int d = t & 63, p = t >> 6;
    float bias = b2[d];
    float acc = 0.f;
    for (int n = p; n < NN; n += 4) {
        int node = b * NN + n;
        float v = dinv[node] * rawB[((size_t)node << 6) + d] + bias;
        acc += v > 0.f ? v : 0.f;
    }
    part[p][d] = acc;
    __syncthreads();
    if (t < 64) {
        float s = part[0][t] + part[1][t] + part[2][t] + part[3][t];
        pooled[t] = s * (1.0f / NN);
    }
    __syncthreads();
    if (t < 2) {
        float o = bh[t];
        for (int k = 0; k < 64; ++k) o += pooled[k] * Wh[k * 2 + t];
        out[b * 2 + t] = o;
    }
}

extern "C" void kernel_launch(void* const* d_in, const int* in_sizes, int n_in,
                              void* d_out, int out_size, void* d_ws, size_t ws_size,
                              hipStream_t stream) {
    const float* x  = (const float*)d_in[0];
    const int*   ei = (const int*)d_in[1];
    const float* W1 = (const float*)d_in[2];
    const float* b1 = (const float*)d_in[3];
    const float* W2 = (const float*)d_in[4];
    const float* b2 = (const float*)d_in[5];
    const float* Wh = (const float*)d_in[6];
    const float* bh = (const float*)d_in[7];
    float* out = (float*)d_out;

    float* ws   = (float*)d_ws;
    float* bufA = ws;                          // NV*DD  (g / gather source)
    float* bufB = bufA + (size_t)NV * DD;      // NV*DD  (raw aggregate)
    float* h0   = bufB + (size_t)NV * DD;      // NV*FF
    float* dinv = h0 + (size_t)NV * FF;        // NV
    int*   degi = (int*)(dinv + NV);           // NV
    int*   rowptr = degi + NV;                 // NV+1
    int*   cursor = rowptr + NV + 1;           // NV
    int*   sorted_src = cursor + NV;           // NE
    int*   bsums = sorted_src + NE;            // NBLK
    int*   boffs = bsums + NBLK;               // NBLK
    int*   flag = boffs + NBLK;                // 1

    // --- CSR build ---
    detect_i64_kernel<<<1, 256, 0, stream>>>(ei, flag);
    zero_deg_kernel<<<(NV + 255) / 256, 256, 0, stream>>>(degi);
    tmean_kernel<<<(NV * FF + 255) / 256, 256, 0, stream>>>(x, h0);
    deg_kernel<<<2048, 256, 0, stream>>>(ei, flag, degi);
    dinv_kernel<<<(NV + 255) / 256, 256, 0, stream>>>(degi, dinv);
    scan1_kernel<<<NBLK, 256, 0, stream>>>(degi, rowptr, bsums);
    scan2_kernel<<<1, 256, 0, stream>>>(bsums, boffs, rowptr);
    scan3_kernel<<<NBLK, 256, 0, stream>>>(rowptr, boffs, cursor);
    bin_kernel<<<2048, 256, 0, stream>>>(ei, flag, cursor, sorted_src);

    // --- Layer 1 ---
    transform1_kernel<<<NV * DD / 256, 256, 0, stream>>>(h0, dinv, W1, bufA);
    agg_kernel<<<NV * 64 / 256, 256, 0, stream>>>(rowptr, sorted_src, bufA, bufB);

    // --- Layer 2 (relu/bias of layer 1 fused into transform) ---
    transform2_kernel<<<NV * DD / 256, 256, 0, stream>>>(bufB, dinv, b1, W2, bufA);
    agg_kernel<<<NV * 64 / 256, 256, 0, stream>>>(rowptr, sorted_src, bufA, bufB);

    // --- Pool + head ---
    pool_head_kernel<<<BB, 256, 0, stream>>>(bufB, dinv, b2, Wh, bh, out);
}

// Round 4
// 288.857 us; speedup vs baseline: 2.2777x; 1.3666x over previous
//
#include <hip/hip_runtime.h>
#include <hip/hip_bf16.h>
#include <cstdint>

#define NV 64000      // B*N nodes
#define DD 64         // hidden dim
#define FF 3          // input features
#define NE 1000000    // edges
#define BB 32         // batch (graphs)
#define SS 50         // timesteps
#define NN 2000       // nodes per graph
#define NBLK 250      // scan blocks: 250 * 256 == NV
#define PCH 16        // pooling chunks per graph (NN/PCH = 125 nodes/chunk)

// ---------------------------------------------------------------------------
// Detect whether edge_index arrived as int64 (odd int32 words all zero) or
// int32. Branch is wave-uniform in all consumers.
// ---------------------------------------------------------------------------
__global__ void detect_i64_kernel(const int* __restrict__ ei, int* __restrict__ flag) {
    __shared__ int nz;
    int t = threadIdx.x;
    if (t == 0) nz = 0;
    __syncthreads();
    int local = 0;
    for (int i = t; i < 4096; i += blockDim.x)
        local |= (ei[2 * i + 1] != 0);
    if (local) atomicOr(&nz, 1);
    __syncthreads();
    if (t == 0) *flag = (nz == 0) ? 1 : 0;
}

__global__ void zero_deg_kernel(int* __restrict__ degi) {
    int i = blockIdx.x * blockDim.x + threadIdx.x;
    if (i < NV) degi[i] = 0;
}

// Edge-only dst degree (self loop added later in dinv).
__global__ void deg_kernel(const int* __restrict__ ei32, const int* __restrict__ flag,
                           int* __restrict__ degi) {
    const long long* ei64 = (const long long*)ei32;
    const int is64 = *flag;
    int stride = gridDim.x * blockDim.x;
    for (int e = blockIdx.x * blockDim.x + threadIdx.x; e < NE; e += stride) {
        int d = is64 ? (int)ei64[NE + e] : ei32[NE + e];
        if ((unsigned)d < NV) atomicAdd(&degi[d], 1);
    }
}

__global__ void dinv_kernel(const int* __restrict__ degi, float* __restrict__ dinv) {
    int i = blockIdx.x * blockDim.x + threadIdx.x;
    if (i < NV) dinv[i] = rsqrtf((float)(degi[i] + 1));  // +1 self loop
}

// --- 3-phase hierarchical exclusive scan over degi (64000 = 250 x 256) ---
__global__ __launch_bounds__(256) void scan1_kernel(const int* __restrict__ deg,
                                                    int* __restrict__ rowptr,
                                                    int* __restrict__ bsums) {
    __shared__ int ls[256];
    int t = threadIdx.x;
    int idx = blockIdx.x * 256 + t;
    int v = deg[idx];
    ls[t] = v;
    __syncthreads();
    #pragma unroll
    for (int off = 1; off < 256; off <<= 1) {
        int u = (t >= off) ? ls[t - off] : 0;
        __syncthreads();
        ls[t] += u;
        __syncthreads();
    }
    rowptr[idx] = ls[t] - v;  // exclusive, block-local
    if (t == 255) bsums[blockIdx.x] = ls[255];
}

__global__ __launch_bounds__(256) void scan2_kernel(const int* __restrict__ bsums,
                                                    int* __restrict__ boffs,
                                                    int* __restrict__ rowptr) {
    __shared__ int ls[256];
    int t = threadIdx.x;
    int v = (t < NBLK) ? bsums[t] : 0;
    ls[t] = v;
    __syncthreads();
    #pragma unroll
    for (int off = 1; off < 256; off <<= 1) {
        int u = (t >= off) ? ls[t - off] : 0;
        __syncthreads();
        ls[t] += u;
        __syncthreads();
    }
    if (t < NBLK) boffs[t] = ls[t] - v;
    if (t == NBLK - 1) rowptr[NV] = ls[t];
}

__global__ __launch_bounds__(256) void scan3_kernel(int* __restrict__ rowptr,
                                                    const int* __restrict__ boffs,
                                                    int* __restrict__ cursor) {
    int idx = blockIdx.x * 256 + threadIdx.x;
    int v = rowptr[idx] + boffs[blockIdx.x];
    rowptr[idx] = v;
    cursor[idx] = v;
}

// Bin src ids by dst into sorted_src (CSR column array).
__global__ void bin_kernel(const int* __restrict__ ei32, const int* __restrict__ flag,
                           int* __restrict__ cursor, int* __restrict__ sorted_src) {
    const long long* ei64 = (const long long*)ei32;
    const int is64 = *flag;
    int stride = gridDim.x * blockDim.x;
    for (int e = blockIdx.x * blockDim.x + threadIdx.x; e < NE; e += stride) {
        int s, d;
        if (is64) { s = (int)ei64[e]; d = (int)ei64[NE + e]; }
        else      { s = ei32[e];      d = ei32[NE + e]; }
        if ((unsigned)s < NV && (unsigned)d < NV) {
            int pos = atomicAdd(&cursor[d], 1);
            sorted_src[pos] = s;
        }
    }
}

// h0[node*3+f] = mean over S of x[b][s][n][f]
__global__ void tmean_kernel(const float* __restrict__ x, float* __restrict__ h0) {
    int tid = blockIdx.x * blockDim.x + threadIdx.x;  // over NV*FF
    if (tid >= NV * FF) return;
    int nf = tid % (NN * FF);
    int b  = tid / (NN * FF);
    const float* xp = x + (size_t)b * SS * NN * FF + nf;
    float acc = 0.f;
    #pragma unroll
    for (int s = 0; s < SS; ++s) acc += xp[(size_t)s * NN * FF];
    h0[tid] = acc * (1.0f / SS);
}

// g = dinv[node] * (h0 @ W1)
__global__ void transform1_kernel(const float* __restrict__ h0, const float* __restrict__ dinv,
                                  const float* __restrict__ W1, float* __restrict__ gA) {
    int tid = blockIdx.x * blockDim.x + threadIdx.x;  // NV*DD
    if (tid >= NV * DD) return;
    int node = tid >> 6, d = tid & 63;
    float di = dinv[node];
    gA[tid] = di * (h0[node * 3 + 0] * W1[d] +
                    h0[node * 3 + 1] * W1[64 + d] +
                    h0[node * 3 + 2] * W1[128 + d]);
}

// One wave per dst node: register-accumulate gathered g rows, one 256B store.
__global__ __launch_bounds__(256) void agg_kernel(const int* __restrict__ rowptr,
                                                  const int* __restrict__ srcs,
                                                  const float* __restrict__ g,
                                                  float* __restrict__ raw) {
    int lane = threadIdx.x & 63;
    int node = (blockIdx.x * blockDim.x + threadIdx.x) >> 6;
    if (node >= NV) return;
    int beg = rowptr[node], end = rowptr[node + 1];
    float acc = g[((size_t)node << 6) + lane];  // self loop
    int e = beg;
    for (; e + 4 <= end; e += 4) {
        int s0 = srcs[e], s1 = srcs[e + 1], s2 = srcs[e + 2], s3 = srcs[e + 3];
        float v0 = g[((size_t)s0 << 6) + lane];
        float v1 = g[((size_t)s1 << 6) + lane];
        float v2 = g[((size_t)s2 << 6) + lane];
        float v3 = g[((size_t)s3 << 6) + lane];
        acc += v0 + v1 + v2 + v3;
    }
    for (; e < end; ++e) acc += g[((size_t)srcs[e] << 6) + lane];
    raw[((size_t)node << 6) + lane] = acc;
}

// Fused: h1 = relu(dinv*raw1 + b1); g2 = dinv * (h1 @ W2). W2 + 4 rows in LDS.
__global__ __launch_bounds__(256) void transform2_kernel(const float* __restrict__ raw1,
                                                         const float* __restrict__ dinv,
                                                         const float* __restrict__ b1,
                                                         const float* __restrict__ W2,
                                                         float* __restrict__ gA) {
    __shared__ float W2s[64 * 64];
    __shared__ float rows[4 * 64];
    int t = threadIdx.x;
    for (int i = t; i < 64 * 64; i += 256) W2s[i] = W2[i];
    int base = blockIdx.x * 256;
    int node0 = base >> 6;
    {
        int node = node0 + (t >> 6), d = t & 63;
        float v = dinv[node] * raw1[base + t] + b1[d];
        rows[t] = v > 0.f ? v : 0.f;
    }
    __syncthreads();
    int sub = t >> 6, d = t & 63;
    const float* r = &rows[sub * 64];
    float acc = 0.f;
    #pragma unroll 8
    for (int k = 0; k < 64; ++k) acc += r[k] * W2s[k * 64 + d];
    gA[base + t] = dinv[node0 + sub] * acc;
}

// --- Two-phase pooling ---
// Phase 1: grid = BB*PCH blocks; block (b,c) reduces 125 node-rows with
// relu/bias/dinv fused -> partials[(b*PCH+c)*64 + d].
__global__ __launch_bounds__(256) void pool_part_kernel(const float* __restrict__ rawB,
                                                        const float* __restrict__ dinv,
                                                        const float* __restrict__ b2,
                                                        float* __restrict__ partials) {
    __shared__ float part[4][64];
    int blk = blockIdx.x;
    int b = blk / PCH, c = blk % PCH;
    int t = threadIdx.x;
    int d = t & 63, p = t >> 6;
    const int CHN = NN / PCH;  // 125
    int n0 = b * NN + c * CHN;
    float bias = b2[d];
    float acc = 0.f;
    for (int n = p; n < CHN; n += 4) {
        int node = n0 + n;
        float v = dinv[node] * rawB[((size_t)node << 6) + d] + bias;
        acc += v > 0.f ? v : 0.f;
    }
    part[p][d] = acc;
    __syncthreads();
    if (t < 64) {
        partials[(size_t)blk * 64 + t] =
            part[0][t] + part[1][t] + part[2][t] + part[3][t];
    }
}

// Phase 2: 32 blocks x 64 threads; reduce PCH partials, apply head.
__global__ __launch_bounds__(64) void pool_finish_kernel(const float* __restrict__ partials,
                                                         const float* __restrict__ Wh,
                                                         const float* __restrict__ bh,
                                                         float* __restrict__ out) {
    __shared__ float pooled[64];
    int b = blockIdx.x;
    int t = threadIdx.x;
    float s = 0.f;
    #pragma unroll
    for (int c = 0; c < PCH; ++c)
        s += partials[((size_t)b * PCH + c) * 64 + t];
    pooled[t] = s * (1.0f / NN);
    __syncthreads();
    if (t < 2) {
        float o = bh[t];
        #pragma unroll 16
        for (int k = 0; k < 64; ++k) o += pooled[k] * Wh[k * 2 + t];
        out[b * 2 + t] = o;
    }
}

extern "C" void kernel_launch(void* const* d_in, const int* in_sizes, int n_in,
                              void* d_out, int out_size, void* d_ws, size_t ws_size,
                              hipStream_t stream) {
    const float* x  = (const float*)d_in[0];
    const int*   ei = (const int*)d_in[1];
    const float* W1 = (const float*)d_in[2];
    const float* b1 = (const float*)d_in[3];
    const float* W2 = (const float*)d_in[4];
    const float* b2 = (const float*)d_in[5];
    const float* Wh = (const float*)d_in[6];
    const float* bh = (const float*)d_in[7];
    float* out = (float*)d_out;

    float* ws   = (float*)d_ws;
    float* bufA = ws;                          // NV*DD  (g / gather source)
    float* bufB = bufA + (size_t)NV * DD;      // NV*DD  (raw aggregate)
    float* h0   = bufB + (size_t)NV * DD;      // NV*FF
    float* dinv = h0 + (size_t)NV * FF;        // NV
    float* partials = dinv + NV;               // BB*PCH*64
    int*   degi = (int*)(partials + BB * PCH * 64);  // NV
    int*   rowptr = degi + NV;                 // NV+1
    int*   cursor = rowptr + NV + 1;           // NV
    int*   sorted_src = cursor + NV;           // NE
    int*   bsums = sorted_src + NE;            // NBLK
    int*   boffs = bsums + NBLK;               // NBLK
    int*   flag = boffs + NBLK;                // 1

    // --- CSR build ---
    detect_i64_kernel<<<1, 256, 0, stream>>>(ei, flag);
    zero_deg_kernel<<<(NV + 255) / 256, 256, 0, stream>>>(degi);
    tmean_kernel<<<(NV * FF + 255) / 256, 256, 0, stream>>>(x, h0);
    deg_kernel<<<2048, 256, 0, stream>>>(ei, flag, degi);
    dinv_kernel<<<(NV + 255) / 256, 256, 0, stream>>>(degi, dinv);
    scan1_kernel<<<NBLK, 256, 0, stream>>>(degi, rowptr, bsums);
    scan2_kernel<<<1, 256, 0, stream>>>(bsums, boffs, rowptr);
    scan3_kernel<<<NBLK, 256, 0, stream>>>(rowptr, boffs, cursor);
    bin_kernel<<<2048, 256, 0, stream>>>(ei, flag, cursor, sorted_src);

    // --- Layer 1 ---
    transform1_kernel<<<NV * DD / 256, 256, 0, stream>>>(h0, dinv, W1, bufA);
    agg_kernel<<<NV * 64 / 256, 256, 0, stream>>>(rowptr, sorted_src, bufA, bufB);

    // --- Layer 2 (relu/bias of layer 1 fused into transform) ---
    transform2_kernel<<<NV * DD / 256, 256, 0, stream>>>(bufB, dinv, b1, W2, bufA);
    agg_kernel<<<NV * 64 / 256, 256, 0, stream>>>(rowptr, sorted_src, bufA, bufB);

    // --- Pool + head (two-phase) ---
    pool_part_kernel<<<BB * PCH, 256, 0, stream>>>(bufB, dinv, b2, partials);
    pool_finish_kernel<<<BB, 64, 0, stream>>>(partials, Wh, bh, out);
}